// Round 1
// baseline (536.973 us; speedup 1.0000x reference)
//
#include <hip/hip_runtime.h>
#include <math.h>

#define NPTS 400000
#define NBATCH 8
#define ELEMS_PER_WAVE 1024
#define WAVES_PER_BATCH 392   // ceil(400000/1024)=391, rounded up to 4-wave block multiple
#define BLOCKS_X 98           // 392 waves / 4 waves-per-block
#define K_OUT 64
#define IDX_SENTINEL 0x7fffffff

// comparator: (value desc, index asc) — matches jax.lax.top_k tie-breaking
__device__ __forceinline__ bool better(float av, int ai, float bv, int bi) {
    return (av > bv) || (av == bv && ai < bi);
}

__device__ __forceinline__ void cmp_swap(float& v, int& i, int j, bool keepBetter) {
    float ov = __shfl_xor(v, j);
    int   oi = __shfl_xor(i, j);
    bool ob = better(ov, oi, v, i);
    if (keepBetter ? ob : !ob) { v = ov; i = oi; }
}

// Maintain per-wave top-64 (1 entry/lane, sorted descending by comparator).
// Insert a batch of 64 candidates (one per lane).
__device__ __forceinline__ void wave_topk_insert(float& bv, int& bi, float nv, int ni, int lane) {
    // threshold filter: does anyone beat the current 64th-best?
    float tv = __shfl(bv, 63);
    int   ti = __shfl(bi, 63);
    if (__ballot(better(nv, ni, tv, ti)) == 0ULL) return;

    // bitonic sort of new batch, descending across lanes
#pragma unroll
    for (int k = 2; k <= 64; k <<= 1) {
#pragma unroll
        for (int j = k >> 1; j > 0; j >>= 1) {
            bool keepBetter = (((lane & k) == 0) == ((lane & j) == 0));
            cmp_swap(nv, ni, j, keepBetter);
        }
    }
    // elementwise max vs reversed new list -> exact top-64 of union (bitonic seq)
    float rv = __shfl(nv, lane ^ 63);
    int   ri = __shfl(ni, lane ^ 63);
    if (better(rv, ri, bv, bi)) { bv = rv; bi = ri; }
    // bitonic merge -> fully sorted descending
#pragma unroll
    for (int j = 32; j > 0; j >>= 1) {
        cmp_swap(bv, bi, j, (lane & j) == 0);
    }
}

__global__ __launch_bounds__(256) void mlp_score_topk_k1(
    const float* __restrict__ X,
    const float* __restrict__ W1, const float* __restrict__ b1,
    const float* __restrict__ W2, const float* __restrict__ b2,
    const float* __restrict__ W3, const float* __restrict__ b3,
    int2* __restrict__ cand)
{
    __shared__ float w1t[32 * 16];  // [c][o]
    __shared__ float w2t[16 * 8];   // [c][o]
    __shared__ float w3s[8];
    __shared__ float b1s[16];
    __shared__ float b2s[8];
    __shared__ float b3s;

    int t = threadIdx.x;
    for (int idx = t; idx < 512; idx += 256) w1t[idx] = W1[(idx & 15) * 32 + (idx >> 4)];
    if (t < 128) w2t[t] = W2[(t & 7) * 16 + (t >> 3)];
    if (t < 16)  b1s[t] = b1[t];
    if (t >= 16 && t < 24) w3s[t - 16] = W3[t - 16];
    if (t >= 24 && t < 32) b2s[t - 24] = b2[t - 24];
    if (t == 32) b3s = b3[0];
    __syncthreads();

    int b = blockIdx.y;
    int wave = blockIdx.x * 4 + (t >> 6);
    int lane = t & 63;
    const float* Xb = X + (size_t)b * 32 * NPTS;

    float bv = -INFINITY;
    int   bi = IDX_SENTINEL;

    int waveStart = wave * ELEMS_PER_WAVE;
#pragma unroll 1
    for (int r = 0; r < ELEMS_PER_WAVE / 256; ++r) {
        int n = waveStart + r * 256 + lane * 4;  // quad start; NPTS % 4 == 0
        float z0 = -INFINITY, z1 = -INFINITY, z2 = -INFINITY, z3 = -INFINITY;
        bool valid = (n < NPTS);
        if (valid) {
            float4 a1[16];
#pragma unroll
            for (int o = 0; o < 16; ++o) a1[o] = make_float4(0.f, 0.f, 0.f, 0.f);
#pragma unroll 4
            for (int c = 0; c < 32; ++c) {
                float4 xc = *reinterpret_cast<const float4*>(Xb + (size_t)c * NPTS + n);
#pragma unroll
                for (int o = 0; o < 16; ++o) {
                    float w = w1t[c * 16 + o];
                    a1[o].x = fmaf(w, xc.x, a1[o].x);
                    a1[o].y = fmaf(w, xc.y, a1[o].y);
                    a1[o].z = fmaf(w, xc.z, a1[o].z);
                    a1[o].w = fmaf(w, xc.w, a1[o].w);
                }
            }
            float4 a2[8];
#pragma unroll
            for (int o = 0; o < 8; ++o) a2[o] = make_float4(0.f, 0.f, 0.f, 0.f);
#pragma unroll
            for (int c = 0; c < 16; ++c) {
                float bb = b1s[c];
                float4 h = a1[c];
                h.x = fmaxf(h.x + bb, 0.f);
                h.y = fmaxf(h.y + bb, 0.f);
                h.z = fmaxf(h.z + bb, 0.f);
                h.w = fmaxf(h.w + bb, 0.f);
#pragma unroll
                for (int o = 0; o < 8; ++o) {
                    float w = w2t[c * 8 + o];
                    a2[o].x = fmaf(w, h.x, a2[o].x);
                    a2[o].y = fmaf(w, h.y, a2[o].y);
                    a2[o].z = fmaf(w, h.z, a2[o].z);
                    a2[o].w = fmaf(w, h.w, a2[o].w);
                }
            }
            float4 zacc = make_float4(0.f, 0.f, 0.f, 0.f);
#pragma unroll
            for (int c = 0; c < 8; ++c) {
                float bb = b2s[c];
                float4 h = a2[c];
                h.x = fmaxf(h.x + bb, 0.f);
                h.y = fmaxf(h.y + bb, 0.f);
                h.z = fmaxf(h.z + bb, 0.f);
                h.w = fmaxf(h.w + bb, 0.f);
                float w = w3s[c];
                zacc.x = fmaf(w, h.x, zacc.x);
                zacc.y = fmaf(w, h.y, zacc.y);
                zacc.z = fmaf(w, h.z, zacc.z);
                zacc.w = fmaf(w, h.w, zacc.w);
            }
            // softplus is strictly monotone -> rank by pre-activation z (+b3)
            z0 = zacc.x + b3s;
            z1 = zacc.y + b3s;
            z2 = zacc.z + b3s;
            z3 = zacc.w + b3s;
        }
        int i0 = valid ? (n + 0) : IDX_SENTINEL;
        int i1 = valid ? (n + 1) : IDX_SENTINEL;
        int i2 = valid ? (n + 2) : IDX_SENTINEL;
        int i3 = valid ? (n + 3) : IDX_SENTINEL;
        wave_topk_insert(bv, bi, z0, i0, lane);
        wave_topk_insert(bv, bi, z1, i1, lane);
        wave_topk_insert(bv, bi, z2, i2, lane);
        wave_topk_insert(bv, bi, z3, i3, lane);
    }

    cand[((size_t)b * WAVES_PER_BATCH + wave) * 64 + lane] = make_int2(__float_as_int(bv), bi);
}

__global__ __launch_bounds__(1024) void topk_merge_k2(
    const int2* __restrict__ cand, int* __restrict__ out)
{
    __shared__ int2 sbuf[16 * 64];
    int b = blockIdx.x;
    int t = threadIdx.x;
    int w = t >> 6, lane = t & 63;
    const int2* cb = cand + (size_t)b * (WAVES_PER_BATCH * 64);

    float bv = -INFINITY;
    int   bi = IDX_SENTINEL;
#pragma unroll 1
    for (int r = w; r < WAVES_PER_BATCH; r += 16) {
        int2 p = cb[r * 64 + lane];
        wave_topk_insert(bv, bi, __int_as_float(p.x), p.y, lane);
    }
    sbuf[t] = make_int2(__float_as_int(bv), bi);
    __syncthreads();

    if (w == 0) {
        float fv = -INFINITY;
        int   fi = IDX_SENTINEL;
#pragma unroll 1
        for (int r = 0; r < 16; ++r) {
            int2 p = sbuf[r * 64 + lane];
            wave_topk_insert(fv, fi, __int_as_float(p.x), p.y, lane);
        }
        out[b * K_OUT + lane] = fi;  // rank = lane (sorted desc, ties by index asc)
    }
}

extern "C" void kernel_launch(void* const* d_in, const int* in_sizes, int n_in,
                              void* d_out, int out_size, void* d_ws, size_t ws_size,
                              hipStream_t stream) {
    const float* X  = (const float*)d_in[0];
    // d_in[1] is K (=64), compile-time constant here
    const float* W1 = (const float*)d_in[2];
    const float* b1 = (const float*)d_in[3];
    const float* W2 = (const float*)d_in[4];
    const float* b2 = (const float*)d_in[5];
    const float* W3 = (const float*)d_in[6];
    const float* b3 = (const float*)d_in[7];

    int2* cand = (int2*)d_ws;   // 8 * 392 * 64 * 8 B = 1.6 MB
    int*  out  = (int*)d_out;   // 512 int32

    mlp_score_topk_k1<<<dim3(BLOCKS_X, NBATCH), 256, 0, stream>>>(X, W1, b1, W2, b2, W3, b3, cand);
    topk_merge_k2<<<dim3(NBATCH), 1024, 0, stream>>>(cand, out);
}